// Round 9
// baseline (226.672 us; speedup 1.0000x reference)
//
#include <hip/hip_runtime.h>
#include <cstdint>
#include <cstddef>

#define N_NODES 20000
#define N_EDGES 320000
#define E_TOT   340000   // edges + self loops
#define IN_C    256
#define HID     32
#define HEADS0  4
#define OUT_C   40
#define NEG_SLOPE 0.2f
#define CAT     512      // 4 modules * (4 heads * 32 hid)
#define MH      16       // modules * heads
#define H2S     48       // padded h2 row stride (bf16)

typedef unsigned short ushort_t;
typedef __attribute__((ext_vector_type(8))) short short8v;
typedef __attribute__((ext_vector_type(4))) float f32x4;
typedef __attribute__((ext_vector_type(8))) unsigned short ushort8v;

#define WAVE_FENCE() asm volatile("" ::: "memory")

__device__ inline float bf2f(unsigned short u) {
  union { unsigned int i; float f; } c; c.i = ((unsigned int)u) << 16; return c.f;
}
__device__ inline unsigned short f2bf(float f) {
  union { float f; unsigned int i; } c; c.f = f;
  unsigned int r = c.i + 0x7FFFu + ((c.i >> 16) & 1u);
  return (unsigned short)(r >> 16);
}

// ---------------- prep: W1 pack + W2 pack + degree count (block-range dispatch) ----------------
// blocks [0,64): W1 pack.  [64,76): W2 pack.  [76, 76+DEGB): degree.
#define DEGB ((E_TOT + 255) / 256)

__global__ __launch_bounds__(256) void prep_k(const float* __restrict__ W1,
                                              ushort_t* __restrict__ bhi,
                                              ushort_t* __restrict__ blo,
                                              const float* __restrict__ W2,
                                              ushort_t* __restrict__ b2hi,
                                              ushort_t* __restrict__ b2lo,
                                              const int* __restrict__ ei,
                                              int* __restrict__ deg) {
  int blk = blockIdx.x;
  if (blk < 64) {
    int idx = blk * 256 + threadIdx.x;                 // 0 .. 16383
    int n16  = idx >> 9;
    int k32  = (idx >> 6) & 7;
    int lane = idx & 63;
    int cfull = n16 * 16 + (lane & 15);
    int m = cfull >> 7;
    int c = cfull & 127;
    int kbase = k32 * 32 + (lane >> 4) * 8;
#pragma unroll
    for (int b = 0; b < 8; b++) {
      float v = W1[((m << 8) + kbase + b) * 128 + c];
      ushort_t h = f2bf(v);
      bhi[(size_t)idx * 8 + b] = h;
      blo[(size_t)idx * 8 + b] = f2bf(v - bf2f(h));
    }
  } else if (blk < 76) {
    int idx = (blk - 64) * 256 + threadIdx.x;          // 0 .. 3071
    int n16  = idx >> 10;
    int k32  = (idx >> 6) & 15;
    int lane = idx & 63;
    int n = n16 * 16 + (lane & 15);
    int kbase = k32 * 32 + (lane >> 4) * 8;
#pragma unroll
    for (int b = 0; b < 8; b++) {
      float v = (n < OUT_C) ? W2[(kbase + b) * OUT_C + n] : 0.f;
      ushort_t h = f2bf(v);
      b2hi[(size_t)idx * 8 + b] = h;
      b2lo[(size_t)idx * 8 + b] = f2bf(v - bf2f(h));
    }
  } else {
    int e = (blk - 76) * 256 + threadIdx.x;
    if (e < E_TOT) {
      int d = (e < N_EDGES) ? ei[N_EDGES + e] : (e - N_EDGES);
      atomicAdd(&deg[d], 1);
    }
  }
}

__global__ __launch_bounds__(1024) void scan_k(const int* __restrict__ deg, int* __restrict__ row_ptr) {
  const int C = 20;  // 1024*20 = 20480 >= 20001
  __shared__ int part[1024];
  int t = threadIdx.x;
  int b = t * C;
  int s = 0;
  for (int i = 0; i < C; i++) { int idx = b + i; if (idx < N_NODES) s += deg[idx]; }
  part[t] = s;
  __syncthreads();
  for (int off = 1; off < 1024; off <<= 1) {
    int v = part[t];
    int u = (t >= off) ? part[t - off] : 0;
    __syncthreads();
    part[t] = v + u;
    __syncthreads();
  }
  int run = (t > 0) ? part[t - 1] : 0;
  for (int i = 0; i < C; i++) {
    int idx = b + i;
    if (idx <= N_NODES) {
      row_ptr[idx] = run;
      if (idx < N_NODES) run += deg[idx];
    }
  }
}

// scatter + fused edge-score exp (runs AFTER gemm1, es1/ed1 ready).
// No max-subtraction: exact softmax is shift-invariant; scores are O(+-5).
__global__ __launch_bounds__(256) void scatter_score_k(const int* __restrict__ ei,
                                                       const int* __restrict__ row_ptr,
                                                       int* __restrict__ fill,
                                                       int* __restrict__ csr_src,
                                                       const float* __restrict__ es1,
                                                       const float* __restrict__ ed1,
                                                       ushort_t* __restrict__ exq) {
  int e = blockIdx.x * 256 + threadIdx.x;
  if (e >= E_TOT) return;
  int s, d;
  if (e < N_EDGES) { s = ei[e]; d = ei[N_EDGES + e]; }
  else             { s = e - N_EDGES; d = s; }
  int pos = row_ptr[d] + atomicAdd(&fill[d], 1);
  csr_src[pos] = s;

  const float4* sp = (const float4*)(es1 + (size_t)s * MH);
  const float4* dp = (const float4*)(ed1 + (size_t)d * MH);
  float4 a0 = sp[0], a1 = sp[1], a2 = sp[2], a3 = sp[3];
  float4 b0 = dp[0], b1 = dp[1], b2 = dp[2], b3 = dp[3];
  float v[16] = {a0.x + b0.x, a0.y + b0.y, a0.z + b0.z, a0.w + b0.w,
                 a1.x + b1.x, a1.y + b1.y, a1.z + b1.z, a1.w + b1.w,
                 a2.x + b2.x, a2.y + b2.y, a2.z + b2.z, a2.w + b2.w,
                 a3.x + b3.x, a3.y + b3.y, a3.z + b3.z, a3.w + b3.w};
  ushort8v o0, o1;
#pragma unroll
  for (int i = 0; i < 16; i++) {
    float ev = v[i];
    ev = (ev > 0.f) ? ev : ev * NEG_SLOPE;
    float ex = __expf(ev);
    if (i < 8) o0[i] = f2bf(ex); else o1[i - 8] = f2bf(ex);
  }
  *(ushort8v*)(exq + (size_t)pos * MH)     = o0;
  *(ushort8v*)(exq + (size_t)pos * MH + 8) = o1;
}

// ---------------- Layer-1 GEMM: single-pass over N, A=bf16(x hi), B=hi/lo ----------------
// Block = 32 rows x 512 cols, 4 waves; wave tile 32x128 (2 mf x 8 nf).
// x loaded f32 and converted ONCE; scores fused (4 heads per wave).
__global__ __launch_bounds__(256) void gemm1_mfma_k(const float* __restrict__ x,
                                                    const ushort_t* __restrict__ bhi,
                                                    const ushort_t* __restrict__ blo,
                                                    const float* __restrict__ a_src1,
                                                    const float* __restrict__ a_dst1,
                                                    ushort_t* __restrict__ h1b,
                                                    float* __restrict__ es1,
                                                    float* __restrict__ ed1) {
  int tid = threadIdx.x;
  int wave = tid >> 6, lane = tid & 63;
  int l15 = lane & 15, lhi = lane >> 4;
  int wrow = blockIdx.x * 32;            // 625 blocks * 32 = 20000 exactly
  int n16base = wave * 8;

  f32x4 acc[2][8];
#pragma unroll
  for (int mf = 0; mf < 2; mf++)
#pragma unroll
    for (int nf = 0; nf < 8; nf++) acc[mf][nf] = (f32x4){0.f, 0.f, 0.f, 0.f};

  int arow[2];
#pragma unroll
  for (int mf = 0; mf < 2; mf++) arow[mf] = wrow + mf * 16 + l15;

  for (int ks = 0; ks < 8; ks++) {
    short8v ah[2];
#pragma unroll
    for (int mf = 0; mf < 2; mf++) {
      const float4* xp = (const float4*)(x + (size_t)arow[mf] * IN_C + ks * 32 + lhi * 8);
      float4 f0 = xp[0], f1 = xp[1];
      float av8[8] = {f0.x, f0.y, f0.z, f0.w, f1.x, f1.y, f1.z, f1.w};
#pragma unroll
      for (int j = 0; j < 8; j++) ah[mf][j] = (short)f2bf(av8[j]);
    }
#pragma unroll
    for (int nf = 0; nf < 8; nf++) {
      size_t boff = ((size_t)((n16base + nf) * 8 + ks) * 64 + lane) * 8;
      short8v bh = *(const short8v*)(bhi + boff);
      short8v bl = *(const short8v*)(blo + boff);
      acc[0][nf] = __builtin_amdgcn_mfma_f32_16x16x32_bf16(ah[0], bh, acc[0][nf], 0, 0, 0);
      acc[1][nf] = __builtin_amdgcn_mfma_f32_16x16x32_bf16(ah[1], bh, acc[1][nf], 0, 0, 0);
      acc[0][nf] = __builtin_amdgcn_mfma_f32_16x16x32_bf16(ah[0], bl, acc[0][nf], 0, 0, 0);
      acc[1][nf] = __builtin_amdgcn_mfma_f32_16x16x32_bf16(ah[1], bl, acc[1][nf], 0, 0, 0);
    }
  }

  // h1b store: C/D layout col = lane&15, row = (lane>>4)*4 + reg
#pragma unroll
  for (int mf = 0; mf < 2; mf++) {
    int rbase = wrow + mf * 16 + lhi * 4;
#pragma unroll
    for (int nf = 0; nf < 8; nf++) {
      int col = wave * 128 + nf * 16 + l15;
#pragma unroll
      for (int r = 0; r < 4; r++)
        h1b[(size_t)(rbase + r) * CAT + col] = f2bf(acc[mf][nf][r]);
    }
  }

  // Fused scores: wave covers heads wave*4 .. wave*4+3 (head = col>>5, 2 nf per head).
  float as[8], ad[8];
#pragma unroll
  for (int nf = 0; nf < 8; nf++) {
    int aidx = (wave * 4 + (nf >> 1)) * HID + (nf & 1) * 16 + l15;
    as[nf] = a_src1[aidx];
    ad[nf] = a_dst1[aidx];
  }
#pragma unroll
  for (int mf = 0; mf < 2; mf++) {
#pragma unroll
    for (int r = 0; r < 4; r++) {
      int row = wrow + mf * 16 + lhi * 4 + r;
      float ps[4], pd[4];
#pragma unroll
      for (int h = 0; h < 4; h++) {
        ps[h] = acc[mf][2 * h][r] * as[2 * h] + acc[mf][2 * h + 1][r] * as[2 * h + 1];
        pd[h] = acc[mf][2 * h][r] * ad[2 * h] + acc[mf][2 * h + 1][r] * ad[2 * h + 1];
      }
#pragma unroll
      for (int msk = 1; msk < 16; msk <<= 1) {
#pragma unroll
        for (int h = 0; h < 4; h++) {
          ps[h] += __shfl_xor(ps[h], msk);
          pd[h] += __shfl_xor(pd[h], msk);
        }
      }
      if (l15 == 0) {
#pragma unroll
        for (int h = 0; h < 4; h++) {
          es1[row * MH + wave * 4 + h] = ps[h];
          ed1[row * MH + wave * 4 + h] = pd[h];
        }
      }
    }
  }
}

// ---------------- Layer-1 aggregate + bias + ELU -> single bf16 ----------------
// 4 nodes per block, one wave per node; single pass (alpha-exp precomputed in CSR order).

__global__ __launch_bounds__(256) void agg1_k(const ushort_t* __restrict__ h1b,
                                              const ushort_t* __restrict__ exq,
                                              const int* __restrict__ row_ptr,
                                              const int* __restrict__ csr_src,
                                              const float* __restrict__ b1,
                                              ushort_t* __restrict__ h1e) {
  int w = threadIdx.x >> 6, lane = threadIdx.x & 63;
  int n = blockIdx.x * 4 + w;
  int beg = row_ptr[n];
  int deg = row_ptr[n + 1] - beg;
  int hh = lane >> 2;

  __shared__ float ex_buf[4][64][MH + 1];
  __shared__ int   src_buf[4][64];

  float s_part[MH];
#pragma unroll
  for (int i = 0; i < MH; i++) s_part[i] = 0.f;
  float acc[8];
#pragma unroll
  for (int j = 0; j < 8; j++) acc[j] = 0.f;

  for (int base = 0; base < deg; base += 64) {
    int cnt = min(64, deg - base);
    if (lane < cnt) {
      int p = beg + base + lane;
      src_buf[w][lane] = csr_src[p];
      ushort8v q0 = *(const ushort8v*)(exq + (size_t)p * MH);
      ushort8v q1 = *(const ushort8v*)(exq + (size_t)p * MH + 8);
#pragma unroll
      for (int i = 0; i < 8; i++) {
        float ex = bf2f(q0[i]);
        ex_buf[w][lane][i] = ex;
        s_part[i] += ex;
      }
#pragma unroll
      for (int i = 0; i < 8; i++) {
        float ex = bf2f(q1[i]);
        ex_buf[w][lane][8 + i] = ex;
        s_part[8 + i] += ex;
      }
    }
    WAVE_FENCE();
    int e = 0;
    for (; e + 3 < cnt; e += 4) {
      int s0 = src_buf[w][e + 0], s1 = src_buf[w][e + 1];
      int s2 = src_buf[w][e + 2], s3 = src_buf[w][e + 3];
      float x0 = ex_buf[w][e + 0][hh], x1 = ex_buf[w][e + 1][hh];
      float x2 = ex_buf[w][e + 2][hh], x3 = ex_buf[w][e + 3][hh];
      ushort8v v0 = *(const ushort8v*)(h1b + (size_t)s0 * CAT + lane * 8);
      ushort8v v1 = *(const ushort8v*)(h1b + (size_t)s1 * CAT + lane * 8);
      ushort8v v2 = *(const ushort8v*)(h1b + (size_t)s2 * CAT + lane * 8);
      ushort8v v3 = *(const ushort8v*)(h1b + (size_t)s3 * CAT + lane * 8);
#pragma unroll
      for (int j = 0; j < 8; j++) acc[j] += x0 * bf2f(v0[j]);
#pragma unroll
      for (int j = 0; j < 8; j++) acc[j] += x1 * bf2f(v1[j]);
#pragma unroll
      for (int j = 0; j < 8; j++) acc[j] += x2 * bf2f(v2[j]);
#pragma unroll
      for (int j = 0; j < 8; j++) acc[j] += x3 * bf2f(v3[j]);
    }
    for (; e < cnt; e++) {
      int s = src_buf[w][e];
      float xv = ex_buf[w][e][hh];
      ushort8v hv = *(const ushort8v*)(h1b + (size_t)s * CAT + lane * 8);
#pragma unroll
      for (int j = 0; j < 8; j++) acc[j] += xv * bf2f(hv[j]);
    }
    WAVE_FENCE();
  }

  // denominators: full-wave reduce per mh, keep the one this lane needs (hh)
  float denom = 0.f;
#pragma unroll
  for (int i = 0; i < MH; i++) {
    float v = s_part[i];
    v += __shfl_xor(v, 1);  v += __shfl_xor(v, 2);  v += __shfl_xor(v, 4);
    v += __shfl_xor(v, 8);  v += __shfl_xor(v, 16); v += __shfl_xor(v, 32);
    if (hh == i) denom = v;
  }
  denom += 1e-16f;

  const float4* b1p = (const float4*)(b1 + lane * 8);
  float4 bq0 = b1p[0], bq1 = b1p[1];
  float bv8[8] = {bq0.x, bq0.y, bq0.z, bq0.w, bq1.x, bq1.y, bq1.z, bq1.w};

  ushort8v vhi;
#pragma unroll
  for (int j = 0; j < 8; j++) {
    float o = acc[j] / denom + bv8[j];
    float e = (o > 0.f) ? o : (__expf(o) - 1.f);   // ELU fused
    vhi[j] = f2bf(e);
  }
  *(ushort8v*)(h1e + (size_t)n * CAT + lane * 8) = vhi;
}

// ---------------- Layer-2 GEMM (MFMA, A=bf16, B=hi/lo) + fused score epilogue; h2 bf16 ----------------
__global__ __launch_bounds__(256) void gemm2_mfma_k(const ushort_t* __restrict__ h1e,
                                                    const ushort_t* __restrict__ b2hi,
                                                    const ushort_t* __restrict__ b2lo,
                                                    const float* __restrict__ a_src2,
                                                    const float* __restrict__ a_dst2,
                                                    ushort_t* __restrict__ h2b,
                                                    float* __restrict__ es2,
                                                    float* __restrict__ ed2) {
  int tid = threadIdx.x;
  int wave = tid >> 6, lane = tid & 63;
  int l15 = lane & 15, lhi = lane >> 4;
  int wrow = blockIdx.x * 64 + wave * 16;

  f32x4 acc[3];
#pragma unroll
  for (int nf = 0; nf < 3; nf++) acc[nf] = (f32x4){0.f, 0.f, 0.f, 0.f};

  int r0 = wrow + l15;
  int arow = (r0 < N_NODES) ? r0 : (N_NODES - 1);

  for (int ks = 0; ks < 16; ks++) {
    size_t aoff = (size_t)arow * CAT + ks * 32 + lhi * 8;
    short8v ah = *(const short8v*)(h1e + aoff);
#pragma unroll
    for (int nf = 0; nf < 3; nf++) {
      size_t boff = ((size_t)(nf * 16 + ks) * 64 + lane) * 8;
      short8v bh = *(const short8v*)(b2hi + boff);
      short8v bl = *(const short8v*)(b2lo + boff);
      acc[nf] = __builtin_amdgcn_mfma_f32_16x16x32_bf16(ah, bh, acc[nf], 0, 0, 0);
      acc[nf] = __builtin_amdgcn_mfma_f32_16x16x32_bf16(ah, bl, acc[nf], 0, 0, 0);
    }
  }

  float av[3], bv[3];
#pragma unroll
  for (int nf = 0; nf < 3; nf++) {
    int col = nf * 16 + l15;
    av[nf] = (col < OUT_C) ? a_src2[col] : 0.f;
    bv[nf] = (col < OUT_C) ? a_dst2[col] : 0.f;
  }
#pragma unroll
  for (int r = 0; r < 4; r++) {
    int row = wrow + lhi * 4 + r;
    float ps = acc[0][r] * av[0] + acc[1][r] * av[1] + acc[2][r] * av[2];
    float pd = acc[0][r] * bv[0] + acc[1][r] * bv[1] + acc[2][r] * bv[2];
    ps += __shfl_xor(ps, 1); pd += __shfl_xor(pd, 1);
    ps += __shfl_xor(ps, 2); pd += __shfl_xor(pd, 2);
    ps += __shfl_xor(ps, 4); pd += __shfl_xor(pd, 4);
    ps += __shfl_xor(ps, 8); pd += __shfl_xor(pd, 8);
    if (row < N_NODES) {
#pragma unroll
      for (int nf = 0; nf < 3; nf++)
        h2b[(size_t)row * H2S + nf * 16 + l15] = f2bf(acc[nf][r]);
      if (l15 == 0) { es2[row] = ps; ed2[row] = pd; }
    }
  }
}

// ---------------- Layer-2 edge softmax + aggregate + bias + log_softmax ----------------
// No max pass (shift-invariant); 4 nodes/block, one wave per node; bf16 h2 gather.
__global__ __launch_bounds__(256) void agg2_k(const ushort_t* __restrict__ h2b,
                                              const float* __restrict__ es2,
                                              const float* __restrict__ ed2,
                                              const int* __restrict__ row_ptr,
                                              const int* __restrict__ csr_src,
                                              const float* __restrict__ b2,
                                              float* __restrict__ out) {
  int w = threadIdx.x >> 6, lane = threadIdx.x & 63;
  int n = blockIdx.x * 4 + w;
  int beg = row_ptr[n];
  int deg = row_ptr[n + 1] - beg;
  float edn = ed2[n];

  __shared__ float exb[4][64];
  __shared__ int   srb[4][64];

  float acc = 0.f, ssum = 0.f;
  for (int base = 0; base < deg; base += 64) {
    int cnt = min(64, deg - base);
    if (lane < cnt) {
      int s = csr_src[beg + base + lane];
      srb[w][lane] = s;
      float ev = es2[s] + edn;
      ev = (ev > 0.f) ? ev : ev * NEG_SLOPE;
      float ex = __expf(ev);
      exb[w][lane] = ex;
      ssum += ex;
    }
    WAVE_FENCE();
    int e = 0;
    for (; e + 3 < cnt; e += 4) {
      int s0 = srb[w][e], s1 = srb[w][e + 1], s2 = srb[w][e + 2], s3 = srb[w][e + 3];
      float x0 = exb[w][e], x1 = exb[w][e + 1], x2 = exb[w][e + 2], x3 = exb[w][e + 3];
      if (lane < OUT_C) {
        float v0 = bf2f(h2b[(size_t)s0 * H2S + lane]);
        float v1 = bf2f(h2b[(size_t)s1 * H2S + lane]);
        float v2 = bf2f(h2b[(size_t)s2 * H2S + lane]);
        float v3 = bf2f(h2b[(size_t)s3 * H2S + lane]);
        acc += x0 * v0; acc += x1 * v1; acc += x2 * v2; acc += x3 * v3;
      }
    }
    for (; e < cnt; e++) {
      int s = srb[w][e];
      float xv = exb[w][e];
      if (lane < OUT_C) acc += xv * bf2f(h2b[(size_t)s * H2S + lane]);
    }
    WAVE_FENCE();
  }

  ssum += __shfl_xor(ssum, 1); ssum += __shfl_xor(ssum, 2); ssum += __shfl_xor(ssum, 4);
  ssum += __shfl_xor(ssum, 8); ssum += __shfl_xor(ssum, 16); ssum += __shfl_xor(ssum, 32);

  float val = (lane < OUT_C) ? (acc / (ssum + 1e-16f) + b2[lane]) : -INFINITY;

  float rmax = val;
#pragma unroll
  for (int o = 1; o < 64; o <<= 1) rmax = fmaxf(rmax, __shfl_xor(rmax, o));
  float ex = (lane < OUT_C) ? __expf(val - rmax) : 0.f;
  float sume = ex;
#pragma unroll
  for (int o = 1; o < 64; o <<= 1) sume += __shfl_xor(sume, o);
  if (lane < OUT_C) out[(size_t)n * OUT_C + lane] = val - rmax - __logf(sume);
}

// ---------------- launch ----------------

extern "C" void kernel_launch(void* const* d_in, const int* in_sizes, int n_in,
                              void* d_out, int out_size, void* d_ws, size_t ws_size,
                              hipStream_t stream) {
  const float* x      = (const float*)d_in[0];
  const int*   ei     = (const int*)d_in[1];
  const float* W1     = (const float*)d_in[2];
  const float* a_src1 = (const float*)d_in[3];
  const float* a_dst1 = (const float*)d_in[4];
  const float* b1     = (const float*)d_in[5];
  const float* W2     = (const float*)d_in[6];
  const float* a_src2 = (const float*)d_in[7];
  const float* a_dst2 = (const float*)d_in[8];
  const float* b2     = (const float*)d_in[9];
  float* out = (float*)d_out;

  char* ws = (char*)d_ws;
  size_t off = 0;
  auto alloc = [&](size_t bytes) -> void* {
    void* p = ws + off;
    off += (bytes + 255) & ~(size_t)255;
    return p;
  };
  ushort_t* bhi  = (ushort_t*)alloc((size_t)32 * 8 * 64 * 8 * 2);
  ushort_t* blo  = (ushort_t*)alloc((size_t)32 * 8 * 64 * 8 * 2);
  ushort_t* b2hi = (ushort_t*)alloc((size_t)3 * 16 * 64 * 8 * 2);
  ushort_t* b2lo = (ushort_t*)alloc((size_t)3 * 16 * 64 * 8 * 2);
  ushort_t* h1b  = (ushort_t*)alloc((size_t)N_NODES * CAT * 2);
  ushort_t* h1e  = (ushort_t*)alloc((size_t)N_NODES * CAT * 2);
  ushort_t* exq  = (ushort_t*)alloc((size_t)E_TOT * MH * 2);
  float* es1     = (float*)alloc((size_t)N_NODES * MH * 4);
  float* ed1     = (float*)alloc((size_t)N_NODES * MH * 4);
  ushort_t* h2b  = (ushort_t*)alloc((size_t)N_NODES * H2S * 2);
  float* es2     = (float*)alloc((size_t)N_NODES * 4);
  float* ed2     = (float*)alloc((size_t)N_NODES * 4);
  int*   deg     = (int*)alloc((size_t)N_NODES * 4);
  int*   fill    = (int*)alloc((size_t)N_NODES * 4);
  int*   row_ptr = (int*)alloc((size_t)(N_NODES + 1) * 4);
  int*   csr_src = (int*)alloc((size_t)E_TOT * 4);

  // deg and fill are adjacent 256-aligned allocs: zero both with one memset node
  hipMemsetAsync(deg, 0, (((size_t)N_NODES * 4 + 255) & ~(size_t)255) + (size_t)N_NODES * 4, stream);

  prep_k<<<64 + 12 + DEGB, 256, 0, stream>>>(W1, bhi, blo, W2, b2hi, b2lo, ei, deg);
  scan_k<<<1, 1024, 0, stream>>>(deg, row_ptr);
  gemm1_mfma_k<<<N_NODES / 32, 256, 0, stream>>>(
      x, bhi, blo, a_src1, a_dst1, h1b, es1, ed1);
  scatter_score_k<<<(E_TOT + 255) / 256, 256, 0, stream>>>(
      ei, row_ptr, fill, csr_src, es1, ed1, exq);
  agg1_k<<<N_NODES / 4, 256, 0, stream>>>(h1b, exq, row_ptr, csr_src, b1, h1e);
  gemm2_mfma_k<<<(N_NODES + 63) / 64, 256, 0, stream>>>(h1e, b2hi, b2lo, a_src2, a_dst2, h2b, es2, ed2);
  agg2_k<<<N_NODES / 4, 256, 0, stream>>>(h2b, es2, ed2, row_ptr, csr_src, b2, out);
}

// Round 10
// 184.905 us; speedup vs baseline: 1.2259x; 1.2259x over previous
//
#include <hip/hip_runtime.h>
#include <cstdint>
#include <cstddef>

#define N_NODES 20000
#define N_EDGES 320000
#define E_TOT   340000   // edges + self loops
#define IN_C    256
#define HID     32
#define HEADS0  4
#define OUT_C   40
#define NEG_SLOPE 0.2f
#define CAT     512      // 4 modules * (4 heads * 32 hid)
#define MH      16       // modules * heads
#define H2S     48       // padded h2 row stride (bf16)

typedef unsigned short ushort_t;
typedef __attribute__((ext_vector_type(8))) short short8v;
typedef __attribute__((ext_vector_type(4))) float f32x4;
typedef __attribute__((ext_vector_type(8))) unsigned short ushort8v;

#define WAVE_FENCE() asm volatile("" ::: "memory")

__device__ inline float bf2f(unsigned short u) {
  union { unsigned int i; float f; } c; c.i = ((unsigned int)u) << 16; return c.f;
}
__device__ inline unsigned short f2bf(float f) {
  union { float f; unsigned int i; } c; c.f = f;
  unsigned int r = c.i + 0x7FFFu + ((c.i >> 16) & 1u);
  return (unsigned short)(r >> 16);
}

// ---------------- prep: x->bf16 + W1 pack + W2 pack + degree (block-range dispatch) ----------------
// blocks [0,XCB): x cvt.  [XCB,XCB+64): W1 pack.  [+12): W2 pack.  [+DEGB): degree.
#define XCB  (N_NODES * IN_C / 8 / 256)   // 2500
#define DEGB ((E_TOT + 255) / 256)

__global__ __launch_bounds__(256) void prep_k(const float* __restrict__ x,
                                              ushort_t* __restrict__ xb,
                                              const float* __restrict__ W1,
                                              ushort_t* __restrict__ bhi,
                                              ushort_t* __restrict__ blo,
                                              const float* __restrict__ W2,
                                              ushort_t* __restrict__ b2hi,
                                              ushort_t* __restrict__ b2lo,
                                              const int* __restrict__ ei,
                                              int* __restrict__ deg) {
  int blk = blockIdx.x;
  if (blk < XCB) {
    int i = blk * 256 + threadIdx.x;                   // one 8-float chunk per thread
    const float4* xp = (const float4*)(x + (size_t)i * 8);
    float4 f0 = xp[0], f1 = xp[1];
    float v[8] = {f0.x, f0.y, f0.z, f0.w, f1.x, f1.y, f1.z, f1.w};
    ushort8v o;
#pragma unroll
    for (int j = 0; j < 8; j++) o[j] = f2bf(v[j]);
    *(ushort8v*)(xb + (size_t)i * 8) = o;
  } else if (blk < XCB + 64) {
    int idx = (blk - XCB) * 256 + threadIdx.x;         // 0 .. 16383
    int n16  = idx >> 9;
    int k32  = (idx >> 6) & 7;
    int lane = idx & 63;
    int cfull = n16 * 16 + (lane & 15);
    int m = cfull >> 7;
    int c = cfull & 127;
    int kbase = k32 * 32 + (lane >> 4) * 8;
#pragma unroll
    for (int b = 0; b < 8; b++) {
      float v = W1[((m << 8) + kbase + b) * 128 + c];
      ushort_t h = f2bf(v);
      bhi[(size_t)idx * 8 + b] = h;
      blo[(size_t)idx * 8 + b] = f2bf(v - bf2f(h));
    }
  } else if (blk < XCB + 76) {
    int idx = (blk - XCB - 64) * 256 + threadIdx.x;    // 0 .. 3071
    int n16  = idx >> 10;
    int k32  = (idx >> 6) & 15;
    int lane = idx & 63;
    int n = n16 * 16 + (lane & 15);
    int kbase = k32 * 32 + (lane >> 4) * 8;
#pragma unroll
    for (int b = 0; b < 8; b++) {
      float v = (n < OUT_C) ? W2[(kbase + b) * OUT_C + n] : 0.f;
      ushort_t h = f2bf(v);
      b2hi[(size_t)idx * 8 + b] = h;
      b2lo[(size_t)idx * 8 + b] = f2bf(v - bf2f(h));
    }
  } else {
    int e = (blk - XCB - 76) * 256 + threadIdx.x;
    if (e < E_TOT) {
      int d = (e < N_EDGES) ? ei[N_EDGES + e] : (e - N_EDGES);
      atomicAdd(&deg[d], 1);
    }
  }
}

__global__ __launch_bounds__(1024) void scan_k(const int* __restrict__ deg, int* __restrict__ row_ptr) {
  const int C = 20;  // 1024*20 = 20480 >= 20001
  __shared__ int part[1024];
  int t = threadIdx.x;
  int b = t * C;
  int s = 0;
  for (int i = 0; i < C; i++) { int idx = b + i; if (idx < N_NODES) s += deg[idx]; }
  part[t] = s;
  __syncthreads();
  for (int off = 1; off < 1024; off <<= 1) {
    int v = part[t];
    int u = (t >= off) ? part[t - off] : 0;
    __syncthreads();
    part[t] = v + u;
    __syncthreads();
  }
  int run = (t > 0) ? part[t - 1] : 0;
  for (int i = 0; i < C; i++) {
    int idx = b + i;
    if (idx <= N_NODES) {
      row_ptr[idx] = run;
      if (idx < N_NODES) run += deg[idx];
    }
  }
}

// scatter + fused edge-score exp (runs AFTER gemm1, es1/ed1 ready).
// No max-subtraction: exact softmax is shift-invariant; scores are O(+-5).
__global__ __launch_bounds__(256) void scatter_score_k(const int* __restrict__ ei,
                                                       const int* __restrict__ row_ptr,
                                                       int* __restrict__ fill,
                                                       int* __restrict__ csr_src,
                                                       const float* __restrict__ es1,
                                                       const float* __restrict__ ed1,
                                                       ushort_t* __restrict__ exq) {
  int e = blockIdx.x * 256 + threadIdx.x;
  if (e >= E_TOT) return;
  int s, d;
  if (e < N_EDGES) { s = ei[e]; d = ei[N_EDGES + e]; }
  else             { s = e - N_EDGES; d = s; }
  int pos = row_ptr[d] + atomicAdd(&fill[d], 1);
  csr_src[pos] = s;

  const float4* sp = (const float4*)(es1 + (size_t)s * MH);
  const float4* dp = (const float4*)(ed1 + (size_t)d * MH);
  float4 a0 = sp[0], a1 = sp[1], a2 = sp[2], a3 = sp[3];
  float4 b0 = dp[0], b1 = dp[1], b2 = dp[2], b3 = dp[3];
  float v[16] = {a0.x + b0.x, a0.y + b0.y, a0.z + b0.z, a0.w + b0.w,
                 a1.x + b1.x, a1.y + b1.y, a1.z + b1.z, a1.w + b1.w,
                 a2.x + b2.x, a2.y + b2.y, a2.z + b2.z, a2.w + b2.w,
                 a3.x + b3.x, a3.y + b3.y, a3.z + b3.z, a3.w + b3.w};
  ushort8v o0, o1;
#pragma unroll
  for (int i = 0; i < 16; i++) {
    float ev = v[i];
    ev = (ev > 0.f) ? ev : ev * NEG_SLOPE;
    float ex = __expf(ev);
    if (i < 8) o0[i] = f2bf(ex); else o1[i - 8] = f2bf(ex);
  }
  *(ushort8v*)(exq + (size_t)pos * MH)     = o0;
  *(ushort8v*)(exq + (size_t)pos * MH + 8) = o1;
}

// ---------------- Layer-1 GEMM (MFMA, A=bf16 x, B=hi/lo) + fused score epilogue ----------------
// Grid (313, 4); block tile 64 rows x 128 cols; wave tile 32x64.
__global__ __launch_bounds__(256) void gemm1_mfma_k(const ushort_t* __restrict__ xb,
                                                    const ushort_t* __restrict__ bhi,
                                                    const ushort_t* __restrict__ blo,
                                                    const float* __restrict__ a_src1,
                                                    const float* __restrict__ a_dst1,
                                                    ushort_t* __restrict__ h1b,
                                                    float* __restrict__ es1,
                                                    float* __restrict__ ed1) {
  int tid = threadIdx.x;
  int wave = tid >> 6, lane = tid & 63;
  int l15 = lane & 15, lhi = lane >> 4;
  int wrow = blockIdx.x * 64 + (wave & 1) * 32;
  int wcol = blockIdx.y * 128 + (wave >> 1) * 64;
  int n16base = wcol >> 4;

  f32x4 acc[2][4];
#pragma unroll
  for (int mf = 0; mf < 2; mf++)
#pragma unroll
    for (int nf = 0; nf < 4; nf++) acc[mf][nf] = (f32x4){0.f, 0.f, 0.f, 0.f};

  int arow[2];
#pragma unroll
  for (int mf = 0; mf < 2; mf++) {
    int r = wrow + mf * 16 + l15;
    arow[mf] = (r < N_NODES) ? r : (N_NODES - 1);
  }

  for (int ks = 0; ks < 8; ks++) {
    short8v ah[2];
#pragma unroll
    for (int mf = 0; mf < 2; mf++)
      ah[mf] = *(const short8v*)(xb + (size_t)arow[mf] * IN_C + ks * 32 + lhi * 8);
    short8v bh[4], bl[4];
#pragma unroll
    for (int nf = 0; nf < 4; nf++) {
      size_t boff = ((size_t)((n16base + nf) * 8 + ks) * 64 + lane) * 8;
      bh[nf] = *(const short8v*)(bhi + boff);
      bl[nf] = *(const short8v*)(blo + boff);
    }
#pragma unroll
    for (int mf = 0; mf < 2; mf++)
#pragma unroll
      for (int nf = 0; nf < 4; nf++) {
        acc[mf][nf] = __builtin_amdgcn_mfma_f32_16x16x32_bf16(ah[mf], bh[nf], acc[mf][nf], 0, 0, 0);
        acc[mf][nf] = __builtin_amdgcn_mfma_f32_16x16x32_bf16(ah[mf], bl[nf], acc[mf][nf], 0, 0, 0);
      }
  }

  // h1b store: C/D layout col = lane&15, row = (lane>>4)*4 + reg
#pragma unroll
  for (int mf = 0; mf < 2; mf++) {
    int rbase = wrow + mf * 16 + lhi * 4;
#pragma unroll
    for (int nf = 0; nf < 4; nf++) {
      int col = wcol + nf * 16 + l15;
#pragma unroll
      for (int r = 0; r < 4; r++) {
        int row = rbase + r;
        if (row < N_NODES)
          h1b[(size_t)row * CAT + col] = f2bf(acc[mf][nf][r]);
      }
    }
  }

  // Fused scores: this wave's 64 cols = heads mh0, mh0+1 (global head = col>>5).
  int mh0 = wcol >> 5;
  float as[4], ad[4];
#pragma unroll
  for (int nf = 0; nf < 4; nf++) {
    int aidx = (mh0 + (nf >> 1)) * HID + (nf & 1) * 16 + l15;
    as[nf] = a_src1[aidx];
    ad[nf] = a_dst1[aidx];
  }
#pragma unroll
  for (int mf = 0; mf < 2; mf++) {
#pragma unroll
    for (int r = 0; r < 4; r++) {
      int row = wrow + mf * 16 + lhi * 4 + r;
      float ps0 = acc[mf][0][r] * as[0] + acc[mf][1][r] * as[1];
      float ps1 = acc[mf][2][r] * as[2] + acc[mf][3][r] * as[3];
      float pd0 = acc[mf][0][r] * ad[0] + acc[mf][1][r] * ad[1];
      float pd1 = acc[mf][2][r] * ad[2] + acc[mf][3][r] * ad[3];
#pragma unroll
      for (int msk = 1; msk < 16; msk <<= 1) {
        ps0 += __shfl_xor(ps0, msk); ps1 += __shfl_xor(ps1, msk);
        pd0 += __shfl_xor(pd0, msk); pd1 += __shfl_xor(pd1, msk);
      }
      if (l15 == 0 && row < N_NODES) {
        es1[row * MH + mh0]     = ps0;
        es1[row * MH + mh0 + 1] = ps1;
        ed1[row * MH + mh0]     = pd0;
        ed1[row * MH + mh0 + 1] = pd1;
      }
    }
  }
}

// ---------------- Layer-1 aggregate + bias + ELU -> single bf16 ----------------
// 4 nodes per block, one wave per node; single pass (alpha-exp precomputed in CSR order).

__global__ __launch_bounds__(256) void agg1_k(const ushort_t* __restrict__ h1b,
                                              const ushort_t* __restrict__ exq,
                                              const int* __restrict__ row_ptr,
                                              const int* __restrict__ csr_src,
                                              const float* __restrict__ b1,
                                              ushort_t* __restrict__ h1e) {
  int w = threadIdx.x >> 6, lane = threadIdx.x & 63;
  int n = blockIdx.x * 4 + w;
  int beg = row_ptr[n];
  int deg = row_ptr[n + 1] - beg;
  int hh = lane >> 2;

  __shared__ float ex_buf[4][64][MH + 1];
  __shared__ int   src_buf[4][64];

  float s_part[MH];
#pragma unroll
  for (int i = 0; i < MH; i++) s_part[i] = 0.f;
  float acc[8];
#pragma unroll
  for (int j = 0; j < 8; j++) acc[j] = 0.f;

  for (int base = 0; base < deg; base += 64) {
    int cnt = min(64, deg - base);
    if (lane < cnt) {
      int p = beg + base + lane;
      src_buf[w][lane] = csr_src[p];
      ushort8v q0 = *(const ushort8v*)(exq + (size_t)p * MH);
      ushort8v q1 = *(const ushort8v*)(exq + (size_t)p * MH + 8);
#pragma unroll
      for (int i = 0; i < 8; i++) {
        float ex = bf2f(q0[i]);
        ex_buf[w][lane][i] = ex;
        s_part[i] += ex;
      }
#pragma unroll
      for (int i = 0; i < 8; i++) {
        float ex = bf2f(q1[i]);
        ex_buf[w][lane][8 + i] = ex;
        s_part[8 + i] += ex;
      }
    }
    WAVE_FENCE();
    int e = 0;
    for (; e + 3 < cnt; e += 4) {
      int s0 = src_buf[w][e + 0], s1 = src_buf[w][e + 1];
      int s2 = src_buf[w][e + 2], s3 = src_buf[w][e + 3];
      float x0 = ex_buf[w][e + 0][hh], x1 = ex_buf[w][e + 1][hh];
      float x2 = ex_buf[w][e + 2][hh], x3 = ex_buf[w][e + 3][hh];
      ushort8v v0 = *(const ushort8v*)(h1b + (size_t)s0 * CAT + lane * 8);
      ushort8v v1 = *(const ushort8v*)(h1b + (size_t)s1 * CAT + lane * 8);
      ushort8v v2 = *(const ushort8v*)(h1b + (size_t)s2 * CAT + lane * 8);
      ushort8v v3 = *(const ushort8v*)(h1b + (size_t)s3 * CAT + lane * 8);
#pragma unroll
      for (int j = 0; j < 8; j++) acc[j] += x0 * bf2f(v0[j]);
#pragma unroll
      for (int j = 0; j < 8; j++) acc[j] += x1 * bf2f(v1[j]);
#pragma unroll
      for (int j = 0; j < 8; j++) acc[j] += x2 * bf2f(v2[j]);
#pragma unroll
      for (int j = 0; j < 8; j++) acc[j] += x3 * bf2f(v3[j]);
    }
    for (; e < cnt; e++) {
      int s = src_buf[w][e];
      float xv = ex_buf[w][e][hh];
      ushort8v hv = *(const ushort8v*)(h1b + (size_t)s * CAT + lane * 8);
#pragma unroll
      for (int j = 0; j < 8; j++) acc[j] += xv * bf2f(hv[j]);
    }
    WAVE_FENCE();
  }

  // denominators: full-wave reduce per mh, keep the one this lane needs (hh)
  float denom = 0.f;
#pragma unroll
  for (int i = 0; i < MH; i++) {
    float v = s_part[i];
    v += __shfl_xor(v, 1);  v += __shfl_xor(v, 2);  v += __shfl_xor(v, 4);
    v += __shfl_xor(v, 8);  v += __shfl_xor(v, 16); v += __shfl_xor(v, 32);
    if (hh == i) denom = v;
  }
  denom += 1e-16f;

  const float4* b1p = (const float4*)(b1 + lane * 8);
  float4 bq0 = b1p[0], bq1 = b1p[1];
  float bv8[8] = {bq0.x, bq0.y, bq0.z, bq0.w, bq1.x, bq1.y, bq1.z, bq1.w};

  ushort8v vhi;
#pragma unroll
  for (int j = 0; j < 8; j++) {
    float o = acc[j] / denom + bv8[j];
    float e = (o > 0.f) ? o : (__expf(o) - 1.f);   // ELU fused
    vhi[j] = f2bf(e);
  }
  *(ushort8v*)(h1e + (size_t)n * CAT + lane * 8) = vhi;
}

// ---------------- Layer-2 GEMM (MFMA, A=bf16, B=hi/lo) + fused score epilogue; h2 bf16 ----------------
__global__ __launch_bounds__(256) void gemm2_mfma_k(const ushort_t* __restrict__ h1e,
                                                    const ushort_t* __restrict__ b2hi,
                                                    const ushort_t* __restrict__ b2lo,
                                                    const float* __restrict__ a_src2,
                                                    const float* __restrict__ a_dst2,
                                                    ushort_t* __restrict__ h2b,
                                                    float* __restrict__ es2,
                                                    float* __restrict__ ed2) {
  int tid = threadIdx.x;
  int wave = tid >> 6, lane = tid & 63;
  int l15 = lane & 15, lhi = lane >> 4;
  int wrow = blockIdx.x * 64 + wave * 16;

  f32x4 acc[3];
#pragma unroll
  for (int nf = 0; nf < 3; nf++) acc[nf] = (f32x4){0.f, 0.f, 0.f, 0.f};

  int r0 = wrow + l15;
  int arow = (r0 < N_NODES) ? r0 : (N_NODES - 1);

  for (int ks = 0; ks < 16; ks++) {
    size_t aoff = (size_t)arow * CAT + ks * 32 + lhi * 8;
    short8v ah = *(const short8v*)(h1e + aoff);
#pragma unroll
    for (int nf = 0; nf < 3; nf++) {
      size_t boff = ((size_t)(nf * 16 + ks) * 64 + lane) * 8;
      short8v bh = *(const short8v*)(b2hi + boff);
      short8v bl = *(const short8v*)(b2lo + boff);
      acc[nf] = __builtin_amdgcn_mfma_f32_16x16x32_bf16(ah, bh, acc[nf], 0, 0, 0);
      acc[nf] = __builtin_amdgcn_mfma_f32_16x16x32_bf16(ah, bl, acc[nf], 0, 0, 0);
    }
  }

  float av[3], bv[3];
#pragma unroll
  for (int nf = 0; nf < 3; nf++) {
    int col = nf * 16 + l15;
    av[nf] = (col < OUT_C) ? a_src2[col] : 0.f;
    bv[nf] = (col < OUT_C) ? a_dst2[col] : 0.f;
  }
#pragma unroll
  for (int r = 0; r < 4; r++) {
    int row = wrow + lhi * 4 + r;
    float ps = acc[0][r] * av[0] + acc[1][r] * av[1] + acc[2][r] * av[2];
    float pd = acc[0][r] * bv[0] + acc[1][r] * bv[1] + acc[2][r] * bv[2];
    ps += __shfl_xor(ps, 1); pd += __shfl_xor(pd, 1);
    ps += __shfl_xor(ps, 2); pd += __shfl_xor(pd, 2);
    ps += __shfl_xor(ps, 4); pd += __shfl_xor(pd, 4);
    ps += __shfl_xor(ps, 8); pd += __shfl_xor(pd, 8);
    if (row < N_NODES) {
#pragma unroll
      for (int nf = 0; nf < 3; nf++)
        h2b[(size_t)row * H2S + nf * 16 + l15] = f2bf(acc[nf][r]);
      if (l15 == 0) { es2[row] = ps; ed2[row] = pd; }
    }
  }
}

// ---------------- Layer-2 edge softmax + aggregate + bias + log_softmax ----------------
// No max pass (shift-invariant); 4 nodes/block, one wave per node; bf16 h2 gather.
__global__ __launch_bounds__(256) void agg2_k(const ushort_t* __restrict__ h2b,
                                              const float* __restrict__ es2,
                                              const float* __restrict__ ed2,
                                              const int* __restrict__ row_ptr,
                                              const int* __restrict__ csr_src,
                                              const float* __restrict__ b2,
                                              float* __restrict__ out) {
  int w = threadIdx.x >> 6, lane = threadIdx.x & 63;
  int n = blockIdx.x * 4 + w;
  int beg = row_ptr[n];
  int deg = row_ptr[n + 1] - beg;
  float edn = ed2[n];

  __shared__ float exb[4][64];
  __shared__ int   srb[4][64];

  float acc = 0.f, ssum = 0.f;
  for (int base = 0; base < deg; base += 64) {
    int cnt = min(64, deg - base);
    if (lane < cnt) {
      int s = csr_src[beg + base + lane];
      srb[w][lane] = s;
      float ev = es2[s] + edn;
      ev = (ev > 0.f) ? ev : ev * NEG_SLOPE;
      float ex = __expf(ev);
      exb[w][lane] = ex;
      ssum += ex;
    }
    WAVE_FENCE();
    int e = 0;
    for (; e + 3 < cnt; e += 4) {
      int s0 = srb[w][e], s1 = srb[w][e + 1], s2 = srb[w][e + 2], s3 = srb[w][e + 3];
      float x0 = exb[w][e], x1 = exb[w][e + 1], x2 = exb[w][e + 2], x3 = exb[w][e + 3];
      if (lane < OUT_C) {
        float v0 = bf2f(h2b[(size_t)s0 * H2S + lane]);
        float v1 = bf2f(h2b[(size_t)s1 * H2S + lane]);
        float v2 = bf2f(h2b[(size_t)s2 * H2S + lane]);
        float v3 = bf2f(h2b[(size_t)s3 * H2S + lane]);
        acc += x0 * v0; acc += x1 * v1; acc += x2 * v2; acc += x3 * v3;
      }
    }
    for (; e < cnt; e++) {
      int s = srb[w][e];
      float xv = exb[w][e];
      if (lane < OUT_C) acc += xv * bf2f(h2b[(size_t)s * H2S + lane]);
    }
    WAVE_FENCE();
  }

  ssum += __shfl_xor(ssum, 1); ssum += __shfl_xor(ssum, 2); ssum += __shfl_xor(ssum, 4);
  ssum += __shfl_xor(ssum, 8); ssum += __shfl_xor(ssum, 16); ssum += __shfl_xor(ssum, 32);

  float val = (lane < OUT_C) ? (acc / (ssum + 1e-16f) + b2[lane]) : -INFINITY;

  float rmax = val;
#pragma unroll
  for (int o = 1; o < 64; o <<= 1) rmax = fmaxf(rmax, __shfl_xor(rmax, o));
  float ex = (lane < OUT_C) ? __expf(val - rmax) : 0.f;
  float sume = ex;
#pragma unroll
  for (int o = 1; o < 64; o <<= 1) sume += __shfl_xor(sume, o);
  if (lane < OUT_C) out[(size_t)n * OUT_C + lane] = val - rmax - __logf(sume);
}

// ---------------- launch ----------------

extern "C" void kernel_launch(void* const* d_in, const int* in_sizes, int n_in,
                              void* d_out, int out_size, void* d_ws, size_t ws_size,
                              hipStream_t stream) {
  const float* x      = (const float*)d_in[0];
  const int*   ei     = (const int*)d_in[1];
  const float* W1     = (const float*)d_in[2];
  const float* a_src1 = (const float*)d_in[3];
  const float* a_dst1 = (const float*)d_in[4];
  const float* b1     = (const float*)d_in[5];
  const float* W2     = (const float*)d_in[6];
  const float* a_src2 = (const float*)d_in[7];
  const float* a_dst2 = (const float*)d_in[8];
  const float* b2     = (const float*)d_in[9];
  float* out = (float*)d_out;

  char* ws = (char*)d_ws;
  size_t off = 0;
  auto alloc = [&](size_t bytes) -> void* {
    void* p = ws + off;
    off += (bytes + 255) & ~(size_t)255;
    return p;
  };
  ushort_t* xb   = (ushort_t*)alloc((size_t)N_NODES * IN_C * 2);
  ushort_t* bhi  = (ushort_t*)alloc((size_t)32 * 8 * 64 * 8 * 2);
  ushort_t* blo  = (ushort_t*)alloc((size_t)32 * 8 * 64 * 8 * 2);
  ushort_t* b2hi = (ushort_t*)alloc((size_t)3 * 16 * 64 * 8 * 2);
  ushort_t* b2lo = (ushort_t*)alloc((size_t)3 * 16 * 64 * 8 * 2);
  ushort_t* h1b  = (ushort_t*)alloc((size_t)N_NODES * CAT * 2);
  ushort_t* h1e  = (ushort_t*)alloc((size_t)N_NODES * CAT * 2);
  ushort_t* exq  = (ushort_t*)alloc((size_t)E_TOT * MH * 2);
  float* es1     = (float*)alloc((size_t)N_NODES * MH * 4);
  float* ed1     = (float*)alloc((size_t)N_NODES * MH * 4);
  ushort_t* h2b  = (ushort_t*)alloc((size_t)N_NODES * H2S * 2);
  float* es2     = (float*)alloc((size_t)N_NODES * 4);
  float* ed2     = (float*)alloc((size_t)N_NODES * 4);
  int*   deg     = (int*)alloc((size_t)N_NODES * 4);
  int*   fill    = (int*)alloc((size_t)N_NODES * 4);
  int*   row_ptr = (int*)alloc((size_t)(N_NODES + 1) * 4);
  int*   csr_src = (int*)alloc((size_t)E_TOT * 4);

  // deg and fill are adjacent 256-aligned allocs: zero both with one memset node
  hipMemsetAsync(deg, 0, (((size_t)N_NODES * 4 + 255) & ~(size_t)255) + (size_t)N_NODES * 4, stream);

  prep_k<<<XCB + 76 + DEGB, 256, 0, stream>>>(x, xb, W1, bhi, blo, W2, b2hi, b2lo, ei, deg);
  scan_k<<<1, 1024, 0, stream>>>(deg, row_ptr);
  gemm1_mfma_k<<<dim3((N_NODES + 63) / 64, CAT / 128), 256, 0, stream>>>(
      xb, bhi, blo, a_src1, a_dst1, h1b, es1, ed1);
  scatter_score_k<<<(E_TOT + 255) / 256, 256, 0, stream>>>(
      ei, row_ptr, fill, csr_src, es1, ed1, exq);
  agg1_k<<<N_NODES / 4, 256, 0, stream>>>(h1b, exq, row_ptr, csr_src, b1, h1e);
  gemm2_mfma_k<<<(N_NODES + 63) / 64, 256, 0, stream>>>(h1e, b2hi, b2lo, a_src2, a_dst2, h2b, es2, ed2);
  agg2_k<<<N_NODES / 4, 256, 0, stream>>>(h2b, es2, ed2, row_ptr, csr_src, b2, out);
}

// Round 11
// 182.759 us; speedup vs baseline: 1.2403x; 1.0117x over previous
//
#include <hip/hip_runtime.h>
#include <cstdint>
#include <cstddef>

#define N_NODES 20000
#define N_EDGES 320000
#define E_TOT   340000   // edges + self loops
#define IN_C    256
#define HID     32
#define HEADS0  4
#define OUT_C   40
#define NEG_SLOPE 0.2f
#define CAT     512      // 4 modules * (4 heads * 32 hid)
#define MH      16       // modules * heads
#define H2S     48       // padded h2 row stride (bf16)

typedef unsigned short ushort_t;
typedef __attribute__((ext_vector_type(8))) short short8v;
typedef __attribute__((ext_vector_type(4))) float f32x4;
typedef __attribute__((ext_vector_type(8))) unsigned short ushort8v;

#define WAVE_FENCE() asm volatile("" ::: "memory")

__device__ inline float bf2f(unsigned short u) {
  union { unsigned int i; float f; } c; c.i = ((unsigned int)u) << 16; return c.f;
}
__device__ inline unsigned short f2bf(float f) {
  union { float f; unsigned int i; } c; c.f = f;
  unsigned int r = c.i + 0x7FFFu + ((c.i >> 16) & 1u);
  return (unsigned short)(r >> 16);
}

// ---------------- prep: x->bf16 + W1 pack + W2 pack + degree (block-range dispatch) ----------------
#define XCB  (N_NODES * IN_C / 8 / 256)   // 2500
#define DEGB ((E_TOT + 255) / 256)

__global__ __launch_bounds__(256) void prep_k(const float* __restrict__ x,
                                              ushort_t* __restrict__ xb,
                                              const float* __restrict__ W1,
                                              ushort_t* __restrict__ bhi,
                                              ushort_t* __restrict__ blo,
                                              const float* __restrict__ W2,
                                              ushort_t* __restrict__ b2hi,
                                              ushort_t* __restrict__ b2lo,
                                              const int* __restrict__ ei,
                                              int* __restrict__ deg) {
  int blk = blockIdx.x;
  if (blk < XCB) {
    int i = blk * 256 + threadIdx.x;                   // one 8-float chunk per thread
    const float4* xp = (const float4*)(x + (size_t)i * 8);
    float4 f0 = xp[0], f1 = xp[1];
    float v[8] = {f0.x, f0.y, f0.z, f0.w, f1.x, f1.y, f1.z, f1.w};
    ushort8v o;
#pragma unroll
    for (int j = 0; j < 8; j++) o[j] = f2bf(v[j]);
    *(ushort8v*)(xb + (size_t)i * 8) = o;
  } else if (blk < XCB + 64) {
    int idx = (blk - XCB) * 256 + threadIdx.x;         // 0 .. 16383
    int n16  = idx >> 9;
    int k32  = (idx >> 6) & 7;
    int lane = idx & 63;
    int cfull = n16 * 16 + (lane & 15);
    int m = cfull >> 7;
    int c = cfull & 127;
    int kbase = k32 * 32 + (lane >> 4) * 8;
#pragma unroll
    for (int b = 0; b < 8; b++) {
      float v = W1[((m << 8) + kbase + b) * 128 + c];
      ushort_t h = f2bf(v);
      bhi[(size_t)idx * 8 + b] = h;
      blo[(size_t)idx * 8 + b] = f2bf(v - bf2f(h));
    }
  } else if (blk < XCB + 76) {
    int idx = (blk - XCB - 64) * 256 + threadIdx.x;    // 0 .. 3071
    int n16  = idx >> 10;
    int k32  = (idx >> 6) & 15;
    int lane = idx & 63;
    int n = n16 * 16 + (lane & 15);
    int kbase = k32 * 32 + (lane >> 4) * 8;
#pragma unroll
    for (int b = 0; b < 8; b++) {
      float v = (n < OUT_C) ? W2[(kbase + b) * OUT_C + n] : 0.f;
      ushort_t h = f2bf(v);
      b2hi[(size_t)idx * 8 + b] = h;
      b2lo[(size_t)idx * 8 + b] = f2bf(v - bf2f(h));
    }
  } else {
    int e = (blk - XCB - 76) * 256 + threadIdx.x;
    if (e < E_TOT) {
      int d = (e < N_EDGES) ? ei[N_EDGES + e] : (e - N_EDGES);
      atomicAdd(&deg[d], 1);
    }
  }
}

__global__ __launch_bounds__(1024) void scan_k(const int* __restrict__ deg, int* __restrict__ row_ptr) {
  const int C = 20;  // 1024*20 = 20480 >= 20001
  __shared__ int part[1024];
  int t = threadIdx.x;
  int b = t * C;
  int s = 0;
  for (int i = 0; i < C; i++) { int idx = b + i; if (idx < N_NODES) s += deg[idx]; }
  part[t] = s;
  __syncthreads();
  for (int off = 1; off < 1024; off <<= 1) {
    int v = part[t];
    int u = (t >= off) ? part[t - off] : 0;
    __syncthreads();
    part[t] = v + u;
    __syncthreads();
  }
  int run = (t > 0) ? part[t - 1] : 0;
  for (int i = 0; i < C; i++) {
    int idx = b + i;
    if (idx <= N_NODES) {
      row_ptr[idx] = run;
      if (idx < N_NODES) run += deg[idx];
    }
  }
}

// scatter + fused edge-score exp (runs AFTER gemm1, es1/ed1 ready).
// No max-subtraction: exact softmax is shift-invariant; scores are O(+-5).
__global__ __launch_bounds__(256) void scatter_score_k(const int* __restrict__ ei,
                                                       const int* __restrict__ row_ptr,
                                                       int* __restrict__ fill,
                                                       int* __restrict__ csr_src,
                                                       const float* __restrict__ es1,
                                                       const float* __restrict__ ed1,
                                                       ushort_t* __restrict__ exq) {
  int e = blockIdx.x * 256 + threadIdx.x;
  if (e >= E_TOT) return;
  int s, d;
  if (e < N_EDGES) { s = ei[e]; d = ei[N_EDGES + e]; }
  else             { s = e - N_EDGES; d = s; }
  int pos = row_ptr[d] + atomicAdd(&fill[d], 1);
  csr_src[pos] = s;

  const float4* sp = (const float4*)(es1 + (size_t)s * MH);
  const float4* dp = (const float4*)(ed1 + (size_t)d * MH);
  float4 a0 = sp[0], a1 = sp[1], a2 = sp[2], a3 = sp[3];
  float4 b0 = dp[0], b1 = dp[1], b2 = dp[2], b3 = dp[3];
  float v[16] = {a0.x + b0.x, a0.y + b0.y, a0.z + b0.z, a0.w + b0.w,
                 a1.x + b1.x, a1.y + b1.y, a1.z + b1.z, a1.w + b1.w,
                 a2.x + b2.x, a2.y + b2.y, a2.z + b2.z, a2.w + b2.w,
                 a3.x + b3.x, a3.y + b3.y, a3.z + b3.z, a3.w + b3.w};
  ushort8v o0, o1;
#pragma unroll
  for (int i = 0; i < 16; i++) {
    float ev = v[i];
    ev = (ev > 0.f) ? ev : ev * NEG_SLOPE;
    float ex = __expf(ev);
    if (i < 8) o0[i] = f2bf(ex); else o1[i - 8] = f2bf(ex);
  }
  *(ushort8v*)(exq + (size_t)pos * MH)     = o0;
  *(ushort8v*)(exq + (size_t)pos * MH + 8) = o1;
}

// ---------------- Layer-1 GEMM (MFMA, A=bf16 x, B=hi/lo) + fused score epilogue ----------------
// 1280 1D blocks, XCD-swizzled so the 4 col-blocks of a row-block share an XCD:
// id -> row8 = (id>>5)*8 + (id&7), colb = (id>>3)&3.  Same-row blocks differ by 8 -> same XCD L2.
__global__ __launch_bounds__(256) void gemm1_mfma_k(const ushort_t* __restrict__ xb,
                                                    const ushort_t* __restrict__ bhi,
                                                    const ushort_t* __restrict__ blo,
                                                    const float* __restrict__ a_src1,
                                                    const float* __restrict__ a_dst1,
                                                    ushort_t* __restrict__ h1b,
                                                    float* __restrict__ es1,
                                                    float* __restrict__ ed1) {
  int id = blockIdx.x;
  int row8 = ((id >> 5) << 3) | (id & 7);   // 0..319
  int colb = (id >> 3) & 3;                 // 0..3
  if (row8 > 312) return;                   // 313 row-blocks cover 20000 rows

  int tid = threadIdx.x;
  int wave = tid >> 6, lane = tid & 63;
  int l15 = lane & 15, lhi = lane >> 4;
  int wrow = row8 * 64 + (wave & 1) * 32;
  int wcol = colb * 128 + (wave >> 1) * 64;
  int n16base = wcol >> 4;

  f32x4 acc[2][4];
#pragma unroll
  for (int mf = 0; mf < 2; mf++)
#pragma unroll
    for (int nf = 0; nf < 4; nf++) acc[mf][nf] = (f32x4){0.f, 0.f, 0.f, 0.f};

  int arow[2];
#pragma unroll
  for (int mf = 0; mf < 2; mf++) {
    int r = wrow + mf * 16 + l15;
    arow[mf] = (r < N_NODES) ? r : (N_NODES - 1);
  }

  for (int ks = 0; ks < 8; ks++) {
    short8v ah[2];
#pragma unroll
    for (int mf = 0; mf < 2; mf++)
      ah[mf] = *(const short8v*)(xb + (size_t)arow[mf] * IN_C + ks * 32 + lhi * 8);
    short8v bh[4], bl[4];
#pragma unroll
    for (int nf = 0; nf < 4; nf++) {
      size_t boff = ((size_t)((n16base + nf) * 8 + ks) * 64 + lane) * 8;
      bh[nf] = *(const short8v*)(bhi + boff);
      bl[nf] = *(const short8v*)(blo + boff);
    }
#pragma unroll
    for (int mf = 0; mf < 2; mf++)
#pragma unroll
      for (int nf = 0; nf < 4; nf++) {
        acc[mf][nf] = __builtin_amdgcn_mfma_f32_16x16x32_bf16(ah[mf], bh[nf], acc[mf][nf], 0, 0, 0);
        acc[mf][nf] = __builtin_amdgcn_mfma_f32_16x16x32_bf16(ah[mf], bl[nf], acc[mf][nf], 0, 0, 0);
      }
  }

  // h1b store: C/D layout col = lane&15, row = (lane>>4)*4 + reg
#pragma unroll
  for (int mf = 0; mf < 2; mf++) {
    int rbase = wrow + mf * 16 + lhi * 4;
#pragma unroll
    for (int nf = 0; nf < 4; nf++) {
      int col = wcol + nf * 16 + l15;
#pragma unroll
      for (int r = 0; r < 4; r++) {
        int row = rbase + r;
        if (row < N_NODES)
          h1b[(size_t)row * CAT + col] = f2bf(acc[mf][nf][r]);
      }
    }
  }

  // Fused scores: this wave's 64 cols = heads mh0, mh0+1 (global head = col>>5).
  int mh0 = wcol >> 5;
  float as[4], ad[4];
#pragma unroll
  for (int nf = 0; nf < 4; nf++) {
    int aidx = (mh0 + (nf >> 1)) * HID + (nf & 1) * 16 + l15;
    as[nf] = a_src1[aidx];
    ad[nf] = a_dst1[aidx];
  }
#pragma unroll
  for (int mf = 0; mf < 2; mf++) {
#pragma unroll
    for (int r = 0; r < 4; r++) {
      int row = wrow + mf * 16 + lhi * 4 + r;
      float ps0 = acc[mf][0][r] * as[0] + acc[mf][1][r] * as[1];
      float ps1 = acc[mf][2][r] * as[2] + acc[mf][3][r] * as[3];
      float pd0 = acc[mf][0][r] * ad[0] + acc[mf][1][r] * ad[1];
      float pd1 = acc[mf][2][r] * ad[2] + acc[mf][3][r] * ad[3];
#pragma unroll
      for (int msk = 1; msk < 16; msk <<= 1) {
        ps0 += __shfl_xor(ps0, msk); ps1 += __shfl_xor(ps1, msk);
        pd0 += __shfl_xor(pd0, msk); pd1 += __shfl_xor(pd1, msk);
      }
      if (l15 == 0 && row < N_NODES) {
        es1[row * MH + mh0]     = ps0;
        es1[row * MH + mh0 + 1] = ps1;
        ed1[row * MH + mh0]     = pd0;
        ed1[row * MH + mh0 + 1] = pd1;
      }
    }
  }
}

// ---------------- Layer-1 aggregate + bias + ELU -> single bf16 ----------------
// 4 nodes per block, one wave per node; single pass (alpha-exp precomputed in CSR order).

__global__ __launch_bounds__(256) void agg1_k(const ushort_t* __restrict__ h1b,
                                              const ushort_t* __restrict__ exq,
                                              const int* __restrict__ row_ptr,
                                              const int* __restrict__ csr_src,
                                              const float* __restrict__ b1,
                                              ushort_t* __restrict__ h1e) {
  int w = threadIdx.x >> 6, lane = threadIdx.x & 63;
  int n = blockIdx.x * 4 + w;
  int beg = row_ptr[n];
  int deg = row_ptr[n + 1] - beg;
  int hh = lane >> 2;

  __shared__ float ex_buf[4][64][MH + 1];
  __shared__ int   src_buf[4][64];

  float s_part[MH];
#pragma unroll
  for (int i = 0; i < MH; i++) s_part[i] = 0.f;
  float acc[8];
#pragma unroll
  for (int j = 0; j < 8; j++) acc[j] = 0.f;

  for (int base = 0; base < deg; base += 64) {
    int cnt = min(64, deg - base);
    if (lane < cnt) {
      int p = beg + base + lane;
      src_buf[w][lane] = csr_src[p];
      ushort8v q0 = *(const ushort8v*)(exq + (size_t)p * MH);
      ushort8v q1 = *(const ushort8v*)(exq + (size_t)p * MH + 8);
#pragma unroll
      for (int i = 0; i < 8; i++) {
        float ex = bf2f(q0[i]);
        ex_buf[w][lane][i] = ex;
        s_part[i] += ex;
      }
#pragma unroll
      for (int i = 0; i < 8; i++) {
        float ex = bf2f(q1[i]);
        ex_buf[w][lane][8 + i] = ex;
        s_part[8 + i] += ex;
      }
    }
    WAVE_FENCE();
    int e = 0;
    for (; e + 3 < cnt; e += 4) {
      int s0 = src_buf[w][e + 0], s1 = src_buf[w][e + 1];
      int s2 = src_buf[w][e + 2], s3 = src_buf[w][e + 3];
      float x0 = ex_buf[w][e + 0][hh], x1 = ex_buf[w][e + 1][hh];
      float x2 = ex_buf[w][e + 2][hh], x3 = ex_buf[w][e + 3][hh];
      ushort8v v0 = *(const ushort8v*)(h1b + (size_t)s0 * CAT + lane * 8);
      ushort8v v1 = *(const ushort8v*)(h1b + (size_t)s1 * CAT + lane * 8);
      ushort8v v2 = *(const ushort8v*)(h1b + (size_t)s2 * CAT + lane * 8);
      ushort8v v3 = *(const ushort8v*)(h1b + (size_t)s3 * CAT + lane * 8);
#pragma unroll
      for (int j = 0; j < 8; j++) acc[j] += x0 * bf2f(v0[j]);
#pragma unroll
      for (int j = 0; j < 8; j++) acc[j] += x1 * bf2f(v1[j]);
#pragma unroll
      for (int j = 0; j < 8; j++) acc[j] += x2 * bf2f(v2[j]);
#pragma unroll
      for (int j = 0; j < 8; j++) acc[j] += x3 * bf2f(v3[j]);
    }
    for (; e < cnt; e++) {
      int s = src_buf[w][e];
      float xv = ex_buf[w][e][hh];
      ushort8v hv = *(const ushort8v*)(h1b + (size_t)s * CAT + lane * 8);
#pragma unroll
      for (int j = 0; j < 8; j++) acc[j] += xv * bf2f(hv[j]);
    }
    WAVE_FENCE();
  }

  // denominators: full-wave reduce per mh, keep the one this lane needs (hh)
  float denom = 0.f;
#pragma unroll
  for (int i = 0; i < MH; i++) {
    float v = s_part[i];
    v += __shfl_xor(v, 1);  v += __shfl_xor(v, 2);  v += __shfl_xor(v, 4);
    v += __shfl_xor(v, 8);  v += __shfl_xor(v, 16); v += __shfl_xor(v, 32);
    if (hh == i) denom = v;
  }
  denom += 1e-16f;

  const float4* b1p = (const float4*)(b1 + lane * 8);
  float4 bq0 = b1p[0], bq1 = b1p[1];
  float bv8[8] = {bq0.x, bq0.y, bq0.z, bq0.w, bq1.x, bq1.y, bq1.z, bq1.w};

  ushort8v vhi;
#pragma unroll
  for (int j = 0; j < 8; j++) {
    float o = acc[j] / denom + bv8[j];
    float e = (o > 0.f) ? o : (__expf(o) - 1.f);   // ELU fused
    vhi[j] = f2bf(e);
  }
  *(ushort8v*)(h1e + (size_t)n * CAT + lane * 8) = vhi;
}

// ---------------- Layer-2 GEMM: split-K across 4 waves + LDS reduce; h2 bf16 ----------------
// 1250 blocks x 16 rows; wave w covers K slice [w*128, w*128+128).
__global__ __launch_bounds__(256) void gemm2_mfma_k(const ushort_t* __restrict__ h1e,
                                                    const ushort_t* __restrict__ b2hi,
                                                    const ushort_t* __restrict__ b2lo,
                                                    const float* __restrict__ a_src2,
                                                    const float* __restrict__ a_dst2,
                                                    ushort_t* __restrict__ h2b,
                                                    float* __restrict__ es2,
                                                    float* __restrict__ ed2) {
  int tid = threadIdx.x;
  int wave = tid >> 6, lane = tid & 63;
  int l15 = lane & 15, lhi = lane >> 4;
  int wrow = blockIdx.x * 16;

  __shared__ f32x4 part[4][3][64];   // 12 KB

  f32x4 acc[3];
#pragma unroll
  for (int nf = 0; nf < 3; nf++) acc[nf] = (f32x4){0.f, 0.f, 0.f, 0.f};

  int arow = wrow + l15;             // 1250*16 = 20000 exact, no clamp needed

#pragma unroll
  for (int kk = 0; kk < 4; kk++) {
    int ks = wave * 4 + kk;
    size_t aoff = (size_t)arow * CAT + ks * 32 + lhi * 8;
    short8v ah = *(const short8v*)(h1e + aoff);
#pragma unroll
    for (int nf = 0; nf < 3; nf++) {
      size_t boff = ((size_t)(nf * 16 + ks) * 64 + lane) * 8;
      short8v bh = *(const short8v*)(b2hi + boff);
      short8v bl = *(const short8v*)(b2lo + boff);
      acc[nf] = __builtin_amdgcn_mfma_f32_16x16x32_bf16(ah, bh, acc[nf], 0, 0, 0);
      acc[nf] = __builtin_amdgcn_mfma_f32_16x16x32_bf16(ah, bl, acc[nf], 0, 0, 0);
    }
  }

#pragma unroll
  for (int nf = 0; nf < 3; nf++) part[wave][nf][lane] = acc[nf];
  __syncthreads();

  if (wave == 0) {
    f32x4 tot[3];
#pragma unroll
    for (int nf = 0; nf < 3; nf++) {
      f32x4 p0 = part[0][nf][lane], p1 = part[1][nf][lane];
      f32x4 p2 = part[2][nf][lane], p3 = part[3][nf][lane];
      tot[nf] = (p0 + p1) + (p2 + p3);
    }

    float av[3], bv[3];
#pragma unroll
    for (int nf = 0; nf < 3; nf++) {
      int col = nf * 16 + l15;
      av[nf] = (col < OUT_C) ? a_src2[col] : 0.f;
      bv[nf] = (col < OUT_C) ? a_dst2[col] : 0.f;
    }
#pragma unroll
    for (int r = 0; r < 4; r++) {
      int row = wrow + lhi * 4 + r;
      float ps = tot[0][r] * av[0] + tot[1][r] * av[1] + tot[2][r] * av[2];
      float pd = tot[0][r] * bv[0] + tot[1][r] * bv[1] + tot[2][r] * bv[2];
      ps += __shfl_xor(ps, 1); pd += __shfl_xor(pd, 1);
      ps += __shfl_xor(ps, 2); pd += __shfl_xor(pd, 2);
      ps += __shfl_xor(ps, 4); pd += __shfl_xor(pd, 4);
      ps += __shfl_xor(ps, 8); pd += __shfl_xor(pd, 8);
#pragma unroll
      for (int nf = 0; nf < 3; nf++)
        h2b[(size_t)row * H2S + nf * 16 + l15] = f2bf(tot[nf][r]);
      if (l15 == 0) { es2[row] = ps; ed2[row] = pd; }
    }
  }
}

// ---------------- Layer-2 edge softmax + aggregate + bias + log_softmax ----------------
// No max pass (shift-invariant); 4 nodes/block, one wave per node; bf16 h2 gather.
__global__ __launch_bounds__(256) void agg2_k(const ushort_t* __restrict__ h2b,
                                              const float* __restrict__ es2,
                                              const float* __restrict__ ed2,
                                              const int* __restrict__ row_ptr,
                                              const int* __restrict__ csr_src,
                                              const float* __restrict__ b2,
                                              float* __restrict__ out) {
  int w = threadIdx.x >> 6, lane = threadIdx.x & 63;
  int n = blockIdx.x * 4 + w;
  int beg = row_ptr[n];
  int deg = row_ptr[n + 1] - beg;
  float edn = ed2[n];

  __shared__ float exb[4][64];
  __shared__ int   srb[4][64];

  float acc = 0.f, ssum = 0.f;
  for (int base = 0; base < deg; base += 64) {
    int cnt = min(64, deg - base);
    if (lane < cnt) {
      int s = csr_src[beg + base + lane];
      srb[w][lane] = s;
      float ev = es2[s] + edn;
      ev = (ev > 0.f) ? ev : ev * NEG_SLOPE;
      float ex = __expf(ev);
      exb[w][lane] = ex;
      ssum += ex;
    }
    WAVE_FENCE();
    int e = 0;
    for (; e + 3 < cnt; e += 4) {
      int s0 = srb[w][e], s1 = srb[w][e + 1], s2 = srb[w][e + 2], s3 = srb[w][e + 3];
      float x0 = exb[w][e], x1 = exb[w][e + 1], x2 = exb[w][e + 2], x3 = exb[w][e + 3];
      if (lane < OUT_C) {
        float v0 = bf2f(h2b[(size_t)s0 * H2S + lane]);
        float v1 = bf2f(h2b[(size_t)s1 * H2S + lane]);
        float v2 = bf2f(h2b[(size_t)s2 * H2S + lane]);
        float v3 = bf2f(h2b[(size_t)s3 * H2S + lane]);
        acc += x0 * v0; acc += x1 * v1; acc += x2 * v2; acc += x3 * v3;
      }
    }
    for (; e < cnt; e++) {
      int s = srb[w][e];
      float xv = exb[w][e];
      if (lane < OUT_C) acc += xv * bf2f(h2b[(size_t)s * H2S + lane]);
    }
    WAVE_FENCE();
  }

  ssum += __shfl_xor(ssum, 1); ssum += __shfl_xor(ssum, 2); ssum += __shfl_xor(ssum, 4);
  ssum += __shfl_xor(ssum, 8); ssum += __shfl_xor(ssum, 16); ssum += __shfl_xor(ssum, 32);

  float val = (lane < OUT_C) ? (acc / (ssum + 1e-16f) + b2[lane]) : -INFINITY;

  float rmax = val;
#pragma unroll
  for (int o = 1; o < 64; o <<= 1) rmax = fmaxf(rmax, __shfl_xor(rmax, o));
  float ex = (lane < OUT_C) ? __expf(val - rmax) : 0.f;
  float sume = ex;
#pragma unroll
  for (int o = 1; o < 64; o <<= 1) sume += __shfl_xor(sume, o);
  if (lane < OUT_C) out[(size_t)n * OUT_C + lane] = val - rmax - __logf(sume);
}

// ---------------- launch ----------------

extern "C" void kernel_launch(void* const* d_in, const int* in_sizes, int n_in,
                              void* d_out, int out_size, void* d_ws, size_t ws_size,
                              hipStream_t stream) {
  const float* x      = (const float*)d_in[0];
  const int*   ei     = (const int*)d_in[1];
  const float* W1     = (const float*)d_in[2];
  const float* a_src1 = (const float*)d_in[3];
  const float* a_dst1 = (const float*)d_in[4];
  const float* b1     = (const float*)d_in[5];
  const float* W2     = (const float*)d_in[6];
  const float* a_src2 = (const float*)d_in[7];
  const float* a_dst2 = (const float*)d_in[8];
  const float* b2     = (const float*)d_in[9];
  float* out = (float*)d_out;

  char* ws = (char*)d_ws;
  size_t off = 0;
  auto alloc = [&](size_t bytes) -> void* {
    void* p = ws + off;
    off += (bytes + 255) & ~(size_t)255;
    return p;
  };
  ushort_t* xb   = (ushort_t*)alloc((size_t)N_NODES * IN_C * 2);
  ushort_t* bhi  = (ushort_t*)alloc((size_t)32 * 8 * 64 * 8 * 2);
  ushort_t* blo  = (ushort_t*)alloc((size_t)32 * 8 * 64 * 8 * 2);
  ushort_t* b2hi = (ushort_t*)alloc((size_t)3 * 16 * 64 * 8 * 2);
  ushort_t* b2lo = (ushort_t*)alloc((size_t)3 * 16 * 64 * 8 * 2);
  ushort_t* h1b  = (ushort_t*)alloc((size_t)N_NODES * CAT * 2);
  ushort_t* h1e  = (ushort_t*)alloc((size_t)N_NODES * CAT * 2);
  ushort_t* exq  = (ushort_t*)alloc((size_t)E_TOT * MH * 2);
  float* es1     = (float*)alloc((size_t)N_NODES * MH * 4);
  float* ed1     = (float*)alloc((size_t)N_NODES * MH * 4);
  ushort_t* h2b  = (ushort_t*)alloc((size_t)N_NODES * H2S * 2);
  float* es2     = (float*)alloc((size_t)N_NODES * 4);
  float* ed2     = (float*)alloc((size_t)N_NODES * 4);
  int*   deg     = (int*)alloc((size_t)N_NODES * 4);
  int*   fill    = (int*)alloc((size_t)N_NODES * 4);
  int*   row_ptr = (int*)alloc((size_t)(N_NODES + 1) * 4);
  int*   csr_src = (int*)alloc((size_t)E_TOT * 4);

  // deg and fill are adjacent 256-aligned allocs: zero both with one memset node
  hipMemsetAsync(deg, 0, (((size_t)N_NODES * 4 + 255) & ~(size_t)255) + (size_t)N_NODES * 4, stream);

  prep_k<<<XCB + 76 + DEGB, 256, 0, stream>>>(x, xb, W1, bhi, blo, W2, b2hi, b2lo, ei, deg);
  scan_k<<<1, 1024, 0, stream>>>(deg, row_ptr);
  gemm1_mfma_k<<<1280, 256, 0, stream>>>(
      xb, bhi, blo, a_src1, a_dst1, h1b, es1, ed1);
  scatter_score_k<<<(E_TOT + 255) / 256, 256, 0, stream>>>(
      ei, row_ptr, fill, csr_src, es1, ed1, exq);
  agg1_k<<<N_NODES / 4, 256, 0, stream>>>(h1b, exq, row_ptr, csr_src, b1, h1e);
  gemm2_mfma_k<<<N_NODES / 16, 256, 0, stream>>>(h1e, b2hi, b2lo, a_src2, a_dst2, h2b, es2, ed2);
  agg2_k<<<N_NODES / 4, 256, 0, stream>>>(h2b, es2, ed2, row_ptr, csr_src, b2, out);
}